// Round 3
// baseline (2126.938 us; speedup 1.0000x reference)
//
#include <hip/hip_runtime.h>
#include <hip/hip_bf16.h>
#include <stdint.h>

#define LSEQ 512
#define NB   64
#define IMGD 3200
#define EMBD 300
#define HD   256
#define KCH  10   // K=320 in chunks of 32 (256 h + 64 x)

typedef __bf16 bf16x8 __attribute__((ext_vector_type(8)));
typedef float  f32x4  __attribute__((ext_vector_type(4)));

__device__ __forceinline__ unsigned short f2bf(float x) {
  unsigned u = __builtin_bit_cast(unsigned, x);
  u = (u + 0x7FFFu + ((u >> 16) & 1u)) >> 16;
  return (unsigned short)u;
}

// ---------------- K1: init mailbox (BOTH parities) + phrase embed + pack ----
// Wpk layout (bf16): e = ((((j4*4+w)*4+g)*10+kk)*64+l)*8+j
//   k = kk*32 + (l>>4)*8 + j ; col = g*256 + j4*64 + w*16 + (l&15)
//   value = k<256 ? Whh[k][col] : Wih[k-256][col]  (MFMA B-fragment order)
__global__ __launch_bounds__(256) void k1_init_emb(
    const float* __restrict__ phr, const float* __restrict__ Wp,
    const float* __restrict__ bp, const float* __restrict__ Wih,
    const float* __restrict__ Whh, float* __restrict__ emb,
    unsigned* __restrict__ hbuf, unsigned short* __restrict__ Wpk) {
  int tid = threadIdx.x, blk = blockIdx.x;
  int gid = blk * 256 + tid;
  if (gid < 16384) {  // zero both parities: tag=0 everywhere, h=0 (= h_0)
    hbuf[gid] = 0u;
    hbuf[gid + 16384] = 0u;
  }
  for (int e = gid; e < 327680; e += 16384) {
    int j = e & 7;
    int t1 = e >> 3;
    int l = t1 & 63;
    int t2 = t1 >> 6;        // 0..639
    int kk = t2 % 10;
    int t3 = t2 / 10;        // 0..63 = j4*16 + w*4 + g
    int g = t3 & 3, w = (t3 >> 2) & 3, j4 = t3 >> 4;
    int k = kk * 32 + ((l >> 4) << 3) + j;
    int col = g * 256 + j4 * 64 + w * 16 + (l & 15);
    float v = (k < 256) ? Whh[k * 1024 + col] : Wih[(k - 256) * 1024 + col];
    Wpk[e] = f2bf(v);
  }
  if (blk < 16) {
    int b = gid >> 6, f = gid & 63;
    float acc = bp[f];
    for (int k = 0; k < EMBD; ++k) acc += phr[b * EMBD + k] * Wp[k * 64 + f];
    emb[gid] = fmaxf(acc, 0.f);
  }
}

// ---------------- K2: img_fc + fuse (fp32, 32 rows/block) ----------------
__global__ __launch_bounds__(256) void k2_imgfuse(
    const float* __restrict__ img, const float* __restrict__ Wc,
    const float* __restrict__ bc, const float* __restrict__ emb,
    unsigned short* __restrict__ fuse) {
  __shared__ float sX[32 * 65];   // +1 pad: conflict-free x reads
  __shared__ float sW[64 * 64];
  int tid = threadIdx.x, blk = blockIdx.x;
  int r = tid & 31, g = tid >> 5;          // compute map: row, col-group of 8
  int rs = tid >> 3, cs = (tid & 7) * 8;   // staging map
  float acc[8];
#pragma unroll
  for (int j = 0; j < 8; ++j) acc[j] = 0.f;

  for (int k0 = 0; k0 < IMGD; k0 += 64) {
    const float* xsrc = img + (size_t)(blk * 32 + rs) * IMGD + k0 + cs;
    float4 v0 = *(const float4*)xsrc;
    float4 v1 = *(const float4*)(xsrc + 4);
    float* xd = sX + rs * 65 + cs;
    xd[0]=v0.x; xd[1]=v0.y; xd[2]=v0.z; xd[3]=v0.w;
    xd[4]=v1.x; xd[5]=v1.y; xd[6]=v1.z; xd[7]=v1.w;
    const float4* wsrc = (const float4*)(Wc + k0 * 64);
#pragma unroll
    for (int i = 0; i < 4; ++i) ((float4*)sW)[i * 256 + tid] = wsrc[i * 256 + tid];
    __syncthreads();
#pragma unroll 8
    for (int k = 0; k < 64; ++k) {
      float xv = sX[r * 65 + k];
      const float* wr = sW + k * 64 + g * 8;
      float4 wa = *(const float4*)wr;
      float4 wb = *(const float4*)(wr + 4);
      acc[0] += xv * wa.x; acc[1] += xv * wa.y; acc[2] += xv * wa.z; acc[3] += xv * wa.w;
      acc[4] += xv * wb.x; acc[5] += xv * wb.y; acc[6] += xv * wb.z; acc[7] += xv * wb.w;
    }
    __syncthreads();
  }
  int rowg = blk * 32 + r;
  int b = rowg >> 9;
  unsigned pk[4];
#pragma unroll
  for (int j2 = 0; j2 < 4; ++j2) {
    int c = g * 8 + j2 * 2;
    float v0 = fmaxf(acc[j2 * 2] + bc[c], 0.f) * emb[b * 64 + c];
    float v1 = fmaxf(acc[j2 * 2 + 1] + bc[c + 1], 0.f) * emb[b * 64 + c + 1];
    pk[j2] = (unsigned)f2bf(v0) | ((unsigned)f2bf(v1) << 16);
  }
  *(uint4*)(fuse + (size_t)rowg * 64 + g * 8) = make_uint4(pk[0], pk[1], pk[2], pk[3]);
}

// ---------------- K3: persistent LSTM, 16 WGs, weights in VGPRs ----------
// 16 WGs = 4 batch-groups x 4 slices of 64 units. Wave w of WG(grp,j4)
// computes the 4 GATES of units [j4*64+w*16, +16): lane's four accs hold
// i,f,g,o for one (batch,unit) -> no transpose, c-state in VGPR.
// Mailbox atomics are SYSTEM scope: sc0+sc1 force both store and poll to the
// IF$ coherence point, bypassing the stale per-XCD L2 copies that made
// round-2 polls spin ~40x on stale data (VALUBusy evidence).
__global__ __launch_bounds__(256) void k3_lstm(
    const unsigned short* __restrict__ Wpk,
    const float* __restrict__ bih, const float* __restrict__ bhh,
    const unsigned short* __restrict__ fuse,
    unsigned* __restrict__ hbuf, float* __restrict__ outfeats) {
  __shared__ __align__(16) unsigned short sZ[2][16 * 328];  // 16 x (320+8 pad)
  int tid = threadIdx.x;
  int wg  = blockIdx.x;
  int grp = wg & 3;            // batch group
  int j4  = wg >> 2;           // 64-unit slice
  int b0  = grp * 16;
  int w = tid >> 6, l = tid & 63;
  int q = l >> 4, c = l & 15;

  // ---- weights: Bf[gate][chunk] from packed fragments (coalesced b128 loads)
  bf16x8 Bf[4][KCH];
  const bf16x8* wp = (const bf16x8*)Wpk + (size_t)((j4 * 4 + w) * 4) * KCH * 64 + l;
#pragma unroll
  for (int g = 0; g < 4; ++g)
#pragma unroll
    for (int kk = 0; kk < KCH; ++kk)
      Bf[g][kk] = wp[(g * KCH + kk) * 64];
  float bv[4];
#pragma unroll
  for (int g = 0; g < 4; ++g) {
    int colg = g * 256 + j4 * 64 + w * 16 + c;
    bv[g] = bih[colg] + bhh[colg];
  }

  // ---- staging/poll map: thread t -> (row t>>4, unit-group t&15)
  int row = tid >> 4, u16i = tid & 15;
  const unsigned short* fbase = fuse + ((size_t)(b0 + row) * 512) * 64 + u16i * 4;
  unsigned short* zh[2] = {&sZ[0][row * 328 + u16i * 16], &sZ[1][row * 328 + u16i * 16]};
  unsigned short* zx[2] = {&sZ[0][row * 328 + 256 + u16i * 4], &sZ[1][row * 328 + 256 + u16i * 4]};
  const unsigned short* za[2] = {&sZ[0][c * 328 + q * 8], &sZ[1][c * 328 + q * 8]};

  // ---- pointwise map: lane -> unit u, batches q*4+0..3
  int u = j4 * 64 + w * 16 + c;
  float cst[4] = {0.f, 0.f, 0.f, 0.f};
  float* ob = outfeats + ((size_t)(b0 + q * 4) * 512) * 256 + u;
  unsigned* mb = hbuf + (size_t)(b0 + q * 4) * 256 + u;

  for (int step = 0; step < LSEQ; ++step) {
    int p = step & 1;
    // x prefetch: independent of the h chain, overlaps the poll
    uint2 fv = *(const uint2*)(fbase + (size_t)step * 64);
    // ---- poll self-validating mailbox (16 u32 = 8 u64 per thread)
    const unsigned long long* pb =
        (const unsigned long long*)(hbuf + p * 16384 + (b0 + row) * 256 + u16i * 16);
    unsigned long long want = (unsigned long long)(step & 0xFFFF);
    unsigned long long m[8];
    for (;;) {
      bool ok = true;
#pragma unroll
      for (int i = 0; i < 8; ++i)
        m[i] = __hip_atomic_load(pb + i, __ATOMIC_RELAXED, __HIP_MEMORY_SCOPE_SYSTEM);
#pragma unroll
      for (int i = 0; i < 8; ++i)
        ok = ok && (((m[i] >> 16) & 0xFFFFull) == want) && ((m[i] >> 48) == want);
      if (ok) break;
    }
    // ---- stage z = [h | x] into LDS parity p (strip tags, pack bf16 pairs)
    unsigned o0 = (unsigned)((m[0] & 0xFFFFull) | ((m[0] >> 16) & 0xFFFF0000ull));
    unsigned o1 = (unsigned)((m[1] & 0xFFFFull) | ((m[1] >> 16) & 0xFFFF0000ull));
    unsigned o2 = (unsigned)((m[2] & 0xFFFFull) | ((m[2] >> 16) & 0xFFFF0000ull));
    unsigned o3 = (unsigned)((m[3] & 0xFFFFull) | ((m[3] >> 16) & 0xFFFF0000ull));
    unsigned o4 = (unsigned)((m[4] & 0xFFFFull) | ((m[4] >> 16) & 0xFFFF0000ull));
    unsigned o5 = (unsigned)((m[5] & 0xFFFFull) | ((m[5] >> 16) & 0xFFFF0000ull));
    unsigned o6 = (unsigned)((m[6] & 0xFFFFull) | ((m[6] >> 16) & 0xFFFF0000ull));
    unsigned o7 = (unsigned)((m[7] & 0xFFFFull) | ((m[7] >> 16) & 0xFFFF0000ull));
    unsigned short* zhp = p ? zh[1] : zh[0];
    ((uint4*)zhp)[0] = make_uint4(o0, o1, o2, o3);
    ((uint4*)zhp)[1] = make_uint4(o4, o5, o6, o7);
    *(uint2*)(p ? zx[1] : zx[0]) = fv;
    __syncthreads();   // single barrier per step (parity dbuf makes it safe)
    // ---- gates: z(16x320) @ W(320x64cols), weights from registers
    const unsigned short* zap = p ? za[1] : za[0];
    f32x4 a0 = {bv[0], bv[0], bv[0], bv[0]};
    f32x4 a1 = {bv[1], bv[1], bv[1], bv[1]};
    f32x4 a2 = {bv[2], bv[2], bv[2], bv[2]};
    f32x4 a3 = {bv[3], bv[3], bv[3], bv[3]};
#pragma unroll
    for (int kk = 0; kk < KCH; ++kk) {
      bf16x8 A = *(const bf16x8*)(zap + kk * 32);
      a0 = __builtin_amdgcn_mfma_f32_16x16x32_bf16(A, Bf[0][kk], a0, 0, 0, 0);
      a1 = __builtin_amdgcn_mfma_f32_16x16x32_bf16(A, Bf[1][kk], a1, 0, 0, 0);
      a2 = __builtin_amdgcn_mfma_f32_16x16x32_bf16(A, Bf[2][kk], a2, 0, 0, 0);
      a3 = __builtin_amdgcn_mfma_f32_16x16x32_bf16(A, Bf[3][kk], a3, 0, 0, 0);
    }
    // ---- pointwise: lane holds all 4 gates for (batch q*4+r, unit u)
    unsigned tag = (unsigned)((step + 1) & 0xFFFF) << 16;
    unsigned* mbp = mb + ((~step & 1) << 14);   // parity (step+1)&1
#pragma unroll
    for (int r = 0; r < 4; ++r) {
      float zi = a0[r], zf = a1[r], zg = a2[r], zo = a3[r];
      float si = 1.f / (1.f + __expf(-zi));
      float sf = 1.f / (1.f + __expf(-zf));
      float so = 1.f / (1.f + __expf(-zo));
      float e2g = __expf(2.f * zg);
      float tg = (e2g - 1.f) / (e2g + 1.f);
      cst[r] = sf * cst[r] + si * tg;
      float e2c = __expf(2.f * cst[r]);
      float hn = so * (e2c - 1.f) / (e2c + 1.f);
      // publish FIRST (peers are latency-critical), then fire-and-forget out
      __hip_atomic_store(mbp + r * 256, tag | (unsigned)f2bf(hn),
                         __ATOMIC_RELAXED, __HIP_MEMORY_SCOPE_SYSTEM);
      ob[((size_t)r * 512 + step) * 256] = hn;
    }
  }
}

// ---------------- K4: classifier + log_softmax ----------------
__global__ __launch_bounds__(256) void k4_classifier(
    const float* __restrict__ feats, const float* __restrict__ Wc1,
    const float* __restrict__ bc1, const float* __restrict__ Wc2,
    const float* __restrict__ bc2, float* __restrict__ lp) {
  __shared__ float sW[64 * 64];
  __shared__ float sX[16 * 257];
  __shared__ float sH[16 * 68];
  int tid = threadIdx.x, blk = blockIdx.x;
  {
    int rs = tid >> 4, seg = (tid & 15) * 16;
    const float4* src = (const float4*)(feats + (size_t)(blk * 16 + rs) * 256 + seg);
    float* xd = sX + rs * 257 + seg;
#pragma unroll
    for (int i = 0; i < 4; ++i) {
      float4 v = src[i];
      xd[i*4+0]=v.x; xd[i*4+1]=v.y; xd[i*4+2]=v.z; xd[i*4+3]=v.w;
    }
  }
  int r = tid & 15, g = tid >> 4;
  float acc[4] = {0.f, 0.f, 0.f, 0.f};
  for (int c4 = 0; c4 < 4; ++c4) {
    __syncthreads();
#pragma unroll
    for (int i = 0; i < 4; ++i)
      ((float4*)sW)[i * 256 + tid] = ((const float4*)(Wc1 + c4 * 4096))[i * 256 + tid];
    __syncthreads();
#pragma unroll 8
    for (int k = 0; k < 64; ++k) {
      float xv = sX[r * 257 + c4 * 64 + k];
      float4 wv = *(const float4*)(sW + k * 64 + g * 4);
      acc[0] += xv * wv.x; acc[1] += xv * wv.y; acc[2] += xv * wv.z; acc[3] += xv * wv.w;
    }
  }
#pragma unroll
  for (int j = 0; j < 4; ++j) {
    int c = g * 4 + j;
    sH[r * 68 + c] = fmaxf(acc[j] + bc1[c], 0.f);
  }
  __syncthreads();
  if (tid < 16) {
    float l0 = bc2[0], l1 = bc2[1];
    for (int c = 0; c < 64; ++c) {
      float h = sH[tid * 68 + c];
      l0 += h * Wc2[c * 2]; l1 += h * Wc2[c * 2 + 1];
    }
    float mx = fmaxf(l0, l1);
    float lse = mx + logf(__expf(l0 - mx) + __expf(l1 - mx));
    int rowg = blk * 16 + tid;
    lp[rowg * 2]     = l0 - lse;
    lp[rowg * 2 + 1] = l1 - lse;
  }
}

// ---------------- K5: gather selected ----------------
__global__ __launch_bounds__(256) void k5_select(
    const float* __restrict__ feats, const int* __restrict__ six,
    float* __restrict__ sel) {
  int b = blockIdx.x, tid = threadIdx.x;
  int ix = six[b];
  sel[b * 256 + tid] = feats[((size_t)b * 512 + ix) * 256 + tid];
}

extern "C" void kernel_launch(void* const* d_in, const int* in_sizes, int n_in,
                              void* d_out, int out_size, void* d_ws, size_t ws_size,
                              hipStream_t stream) {
  const float* img = (const float*)d_in[0];
  const float* phr = (const float*)d_in[1];
  // d_in[2] = masks (unused by reference)
  const int*   six = (const int*)d_in[3];
  const float* Wc  = (const float*)d_in[4];
  const float* bc  = (const float*)d_in[5];
  const float* Wp  = (const float*)d_in[6];
  const float* bp  = (const float*)d_in[7];
  const float* Wih = (const float*)d_in[8];
  const float* bih = (const float*)d_in[9];
  const float* Whh = (const float*)d_in[10];
  const float* bhh = (const float*)d_in[11];
  const float* Wc1 = (const float*)d_in[12];
  const float* bc1 = (const float*)d_in[13];
  const float* Wc2 = (const float*)d_in[14];
  const float* bc2 = (const float*)d_in[15];

  float* out_lp   = (float*)d_out;        // (64,512,2)
  float* out_feat = out_lp + 65536;       // (64,512,256)
  float* out_sel  = out_feat + 8388608;   // (64,256)

  char* ws = (char*)d_ws;
  float*          emb   = (float*)ws;                              // 16 KB
  unsigned short* fuse  = (unsigned short*)(ws + 16384);           // 4 MB bf16
  unsigned*       hbuf  = (unsigned*)(ws + 4210688);               // 128 KB tagged mailbox
  unsigned short* Wpk   = (unsigned short*)(ws + 4341760);         // 640 KB packed weights

  hipLaunchKernelGGL(k1_init_emb, dim3(64), dim3(256), 0, stream,
                     phr, Wp, bp, Wih, Whh, emb, hbuf, Wpk);
  hipLaunchKernelGGL(k2_imgfuse, dim3(1024), dim3(256), 0, stream,
                     img, Wc, bc, emb, fuse);
  hipLaunchKernelGGL(k3_lstm, dim3(16), dim3(256), 0, stream,
                     Wpk, bih, bhh, fuse, hbuf, out_feat);
  hipLaunchKernelGGL(k4_classifier, dim3(2048), dim3(256), 0, stream,
                     out_feat, Wc1, bc1, Wc2, bc2, out_lp);
  hipLaunchKernelGGL(k5_select, dim3(64), dim3(256), 0, stream,
                     out_feat, six, out_sel);
}

// Round 4
// 1783.435 us; speedup vs baseline: 1.1926x; 1.1926x over previous
//
#include <hip/hip_runtime.h>
#include <hip/hip_bf16.h>
#include <stdint.h>

#define LSEQ 512
#define NB   64
#define IMGD 3200
#define EMBD 300
#define HD   256
#define KCH  10   // K=320 in chunks of 32 (256 h + 64 x)

typedef __bf16 bf16x8 __attribute__((ext_vector_type(8)));
typedef float  f32x4  __attribute__((ext_vector_type(4)));

__device__ __forceinline__ unsigned short f2bf(float x) {
  unsigned u = __builtin_bit_cast(unsigned, x);
  u = (u + 0x7FFFu + ((u >> 16) & 1u)) >> 16;
  return (unsigned short)u;
}

// ---------------- K1: init mailbox (BOTH parities) + phrase embed + pack ----
// Wpk layout (bf16): e = ((((j4*4+w)*4+g)*10+kk)*64+l)*8+j
//   k = kk*32 + (l>>4)*8 + j ; col = g*256 + j4*64 + w*16 + (l&15)
//   value = k<256 ? Whh[k][col] : Wih[k-256][col]  (MFMA B-fragment order)
__global__ __launch_bounds__(256) void k1_init_emb(
    const float* __restrict__ phr, const float* __restrict__ Wp,
    const float* __restrict__ bp, const float* __restrict__ Wih,
    const float* __restrict__ Whh, float* __restrict__ emb,
    unsigned* __restrict__ hbuf, unsigned short* __restrict__ Wpk) {
  int tid = threadIdx.x, blk = blockIdx.x;
  int gid = blk * 256 + tid;
  if (gid < 16384) {  // zero both parities: tag=0 everywhere, h=0 (= h_0)
    hbuf[gid] = 0u;
    hbuf[gid + 16384] = 0u;
  }
  for (int e = gid; e < 327680; e += 16384) {
    int j = e & 7;
    int t1 = e >> 3;
    int l = t1 & 63;
    int t2 = t1 >> 6;        // 0..639
    int kk = t2 % 10;
    int t3 = t2 / 10;        // 0..63 = j4*16 + w*4 + g
    int g = t3 & 3, w = (t3 >> 2) & 3, j4 = t3 >> 4;
    int k = kk * 32 + ((l >> 4) << 3) + j;
    int col = g * 256 + j4 * 64 + w * 16 + (l & 15);
    float v = (k < 256) ? Whh[k * 1024 + col] : Wih[(k - 256) * 1024 + col];
    Wpk[e] = f2bf(v);
  }
  if (blk < 16) {
    int b = gid >> 6, f = gid & 63;
    float acc = bp[f];
    for (int k = 0; k < EMBD; ++k) acc += phr[b * EMBD + k] * Wp[k * 64 + f];
    emb[gid] = fmaxf(acc, 0.f);
  }
}

// ---------------- K2: img_fc + fuse (fp32, 32 rows/block) ----------------
__global__ __launch_bounds__(256) void k2_imgfuse(
    const float* __restrict__ img, const float* __restrict__ Wc,
    const float* __restrict__ bc, const float* __restrict__ emb,
    unsigned short* __restrict__ fuse) {
  __shared__ float sX[32 * 65];   // +1 pad: conflict-free x reads
  __shared__ float sW[64 * 64];
  int tid = threadIdx.x, blk = blockIdx.x;
  int r = tid & 31, g = tid >> 5;          // compute map: row, col-group of 8
  int rs = tid >> 3, cs = (tid & 7) * 8;   // staging map
  float acc[8];
#pragma unroll
  for (int j = 0; j < 8; ++j) acc[j] = 0.f;

  for (int k0 = 0; k0 < IMGD; k0 += 64) {
    const float* xsrc = img + (size_t)(blk * 32 + rs) * IMGD + k0 + cs;
    float4 v0 = *(const float4*)xsrc;
    float4 v1 = *(const float4*)(xsrc + 4);
    float* xd = sX + rs * 65 + cs;
    xd[0]=v0.x; xd[1]=v0.y; xd[2]=v0.z; xd[3]=v0.w;
    xd[4]=v1.x; xd[5]=v1.y; xd[6]=v1.z; xd[7]=v1.w;
    const float4* wsrc = (const float4*)(Wc + k0 * 64);
#pragma unroll
    for (int i = 0; i < 4; ++i) ((float4*)sW)[i * 256 + tid] = wsrc[i * 256 + tid];
    __syncthreads();
#pragma unroll 8
    for (int k = 0; k < 64; ++k) {
      float xv = sX[r * 65 + k];
      const float* wr = sW + k * 64 + g * 8;
      float4 wa = *(const float4*)wr;
      float4 wb = *(const float4*)(wr + 4);
      acc[0] += xv * wa.x; acc[1] += xv * wa.y; acc[2] += xv * wa.z; acc[3] += xv * wa.w;
      acc[4] += xv * wb.x; acc[5] += xv * wb.y; acc[6] += xv * wb.z; acc[7] += xv * wb.w;
    }
    __syncthreads();
  }
  int rowg = blk * 32 + r;
  int b = rowg >> 9;
  unsigned pk[4];
#pragma unroll
  for (int j2 = 0; j2 < 4; ++j2) {
    int c = g * 8 + j2 * 2;
    float v0 = fmaxf(acc[j2 * 2] + bc[c], 0.f) * emb[b * 64 + c];
    float v1 = fmaxf(acc[j2 * 2 + 1] + bc[c + 1], 0.f) * emb[b * 64 + c + 1];
    pk[j2] = (unsigned)f2bf(v0) | ((unsigned)f2bf(v1) << 16);
  }
  *(uint4*)(fuse + (size_t)rowg * 64 + g * 8) = make_uint4(pk[0], pk[1], pk[2], pk[3]);
}

// ---------------- K3: persistent LSTM, 32 WGs, same-XCD groups ----------
// 32 WGs = 8 batch-groups (8 batches) x 4 slices (64 units). Group g's
// members are blockIdx {g, g+8, g+16, g+24} == g (mod 8) -> all on ONE XCD
// under round-robin dispatch, so the h-exchange lives in the shared local L2
// (agent-scope atomics, sc0): store->load visibility ~200-300 cy instead of
// the ~5000 cy cross-XCD invalidate latency measured in rounds 1-3.
// M=8: MFMA rows 8-15 are garbage (lanes q>=2 skip pointwise/stores).
__global__ __launch_bounds__(256, 1) void k3_lstm(
    const unsigned short* __restrict__ Wpk,
    const float* __restrict__ bih, const float* __restrict__ bhh,
    const unsigned short* __restrict__ fuse,
    unsigned* __restrict__ hbuf, float* __restrict__ outfeats) {
  __shared__ __align__(16) unsigned short sZ[2][8 * 328];  // 8 x (320+8 pad)
  int tid = threadIdx.x;
  int wg  = blockIdx.x;
  int grp = wg & 7;            // batch group == XCD id (mod-8 placement)
  int j4  = wg >> 3;           // 64-unit slice
  int b0  = grp * 8;
  int w = tid >> 6, l = tid & 63;
  int q = l >> 4, c = l & 15;

  // ---- weights: Bf[gate][chunk] from packed fragments (coalesced b128 loads)
  bf16x8 Bf[4][KCH];
  const bf16x8* wp = (const bf16x8*)Wpk + (size_t)((j4 * 4 + w) * 4) * KCH * 64 + l;
#pragma unroll
  for (int g = 0; g < 4; ++g)
#pragma unroll
    for (int kk = 0; kk < KCH; ++kk)
      Bf[g][kk] = wp[(g * KCH + kk) * 64];
  float bv[4];
#pragma unroll
  for (int g = 0; g < 4; ++g) {
    int colg = g * 256 + j4 * 64 + w * 16 + c;
    bv[g] = bih[colg] + bhh[colg];
  }

  // ---- staging/poll map: thread t -> (row t>>5, unit-octet t&31)
  int row = tid >> 5, u8i = tid & 31;
  const unsigned short* fbase = fuse + ((size_t)(b0 + row) * 512) * 64 + u8i * 2;
  unsigned short* zh[2] = {&sZ[0][row * 328 + u8i * 8], &sZ[1][row * 328 + u8i * 8]};
  unsigned short* zx[2] = {&sZ[0][row * 328 + 256 + u8i * 2], &sZ[1][row * 328 + 256 + u8i * 2]};
  const unsigned short* za[2] = {&sZ[0][(c & 7) * 328 + q * 8], &sZ[1][(c & 7) * 328 + q * 8]};

  // ---- pointwise map (lanes q<2 only): lane -> unit u, batches q*4+0..3
  int u = j4 * 64 + w * 16 + c;
  float cst[4] = {0.f, 0.f, 0.f, 0.f};
  float* ob = outfeats + ((size_t)(b0 + q * 4) * 512) * 256 + u;
  unsigned* mb = hbuf + (size_t)(b0 + q * 4) * 256 + u;

  for (int step = 0; step < LSEQ; ++step) {
    int p = step & 1;
    // x prefetch: independent of the h chain, overlaps the poll
    unsigned fv = *(const unsigned*)(fbase + (size_t)step * 64);
    // ---- poll self-validating mailbox (8 u32 = 4 u64 per thread)
    const unsigned long long* pb =
        (const unsigned long long*)(hbuf + p * 16384 + (b0 + row) * 256 + u8i * 8);
    unsigned long long want = (unsigned long long)(step & 0xFFFF);
    unsigned long long m[4];
    for (;;) {
      bool ok = true;
#pragma unroll
      for (int i = 0; i < 4; ++i)
        m[i] = __hip_atomic_load(pb + i, __ATOMIC_RELAXED, __HIP_MEMORY_SCOPE_AGENT);
#pragma unroll
      for (int i = 0; i < 4; ++i)
        ok = ok && (((m[i] >> 16) & 0xFFFFull) == want) && ((m[i] >> 48) == want);
      if (ok) break;
    }
    // ---- stage z = [h | x] into LDS parity p (strip tags, pack bf16 pairs)
    unsigned o0 = (unsigned)((m[0] & 0xFFFFull) | ((m[0] >> 16) & 0xFFFF0000ull));
    unsigned o1 = (unsigned)((m[1] & 0xFFFFull) | ((m[1] >> 16) & 0xFFFF0000ull));
    unsigned o2 = (unsigned)((m[2] & 0xFFFFull) | ((m[2] >> 16) & 0xFFFF0000ull));
    unsigned o3 = (unsigned)((m[3] & 0xFFFFull) | ((m[3] >> 16) & 0xFFFF0000ull));
    *(uint4*)(p ? zh[1] : zh[0]) = make_uint4(o0, o1, o2, o3);
    *(unsigned*)(p ? zx[1] : zx[0]) = fv;
    __syncthreads();   // single barrier per step (parity dbuf makes it safe)
    // ---- gates: z(8x320) @ W(320x64cols), weights from registers
    const unsigned short* zap = p ? za[1] : za[0];
    f32x4 a0 = {bv[0], bv[0], bv[0], bv[0]};
    f32x4 a1 = {bv[1], bv[1], bv[1], bv[1]};
    f32x4 a2 = {bv[2], bv[2], bv[2], bv[2]};
    f32x4 a3 = {bv[3], bv[3], bv[3], bv[3]};
#pragma unroll
    for (int kk = 0; kk < KCH; ++kk) {
      bf16x8 A = *(const bf16x8*)(zap + kk * 32);
      a0 = __builtin_amdgcn_mfma_f32_16x16x32_bf16(A, Bf[0][kk], a0, 0, 0, 0);
      a1 = __builtin_amdgcn_mfma_f32_16x16x32_bf16(A, Bf[1][kk], a1, 0, 0, 0);
      a2 = __builtin_amdgcn_mfma_f32_16x16x32_bf16(A, Bf[2][kk], a2, 0, 0, 0);
      a3 = __builtin_amdgcn_mfma_f32_16x16x32_bf16(A, Bf[3][kk], a3, 0, 0, 0);
    }
    // ---- pointwise (lanes q<2): lane holds all 4 gates for (batch q*4+r, u)
    if (q < 2) {
      unsigned tag = (unsigned)((step + 1) & 0xFFFF) << 16;
      unsigned* mbp = mb + ((~step & 1) << 14);   // parity (step+1)&1
#pragma unroll
      for (int r = 0; r < 4; ++r) {
        float zi = a0[r], zf = a1[r], zg = a2[r], zo = a3[r];
        float si = 1.f / (1.f + __expf(-zi));
        float sf = 1.f / (1.f + __expf(-zf));
        float so = 1.f / (1.f + __expf(-zo));
        float e2g = __expf(2.f * zg);
        float tg = (e2g - 1.f) / (e2g + 1.f);
        cst[r] = sf * cst[r] + si * tg;
        float e2c = __expf(2.f * cst[r]);
        float hn = so * (e2c - 1.f) / (e2c + 1.f);
        // publish FIRST (peers are latency-critical), then fire-and-forget out
        __hip_atomic_store(mbp + r * 256, tag | (unsigned)f2bf(hn),
                           __ATOMIC_RELAXED, __HIP_MEMORY_SCOPE_AGENT);
        ob[((size_t)r * 512 + step) * 256] = hn;
      }
    }
  }
}

// ---------------- K4: classifier + log_softmax ----------------
__global__ __launch_bounds__(256) void k4_classifier(
    const float* __restrict__ feats, const float* __restrict__ Wc1,
    const float* __restrict__ bc1, const float* __restrict__ Wc2,
    const float* __restrict__ bc2, float* __restrict__ lp) {
  __shared__ float sW[64 * 64];
  __shared__ float sX[16 * 257];
  __shared__ float sH[16 * 68];
  int tid = threadIdx.x, blk = blockIdx.x;
  {
    int rs = tid >> 4, seg = (tid & 15) * 16;
    const float4* src = (const float4*)(feats + (size_t)(blk * 16 + rs) * 256 + seg);
    float* xd = sX + rs * 257 + seg;
#pragma unroll
    for (int i = 0; i < 4; ++i) {
      float4 v = src[i];
      xd[i*4+0]=v.x; xd[i*4+1]=v.y; xd[i*4+2]=v.z; xd[i*4+3]=v.w;
    }
  }
  int r = tid & 15, g = tid >> 4;
  float acc[4] = {0.f, 0.f, 0.f, 0.f};
  for (int c4 = 0; c4 < 4; ++c4) {
    __syncthreads();
#pragma unroll
    for (int i = 0; i < 4; ++i)
      ((float4*)sW)[i * 256 + tid] = ((const float4*)(Wc1 + c4 * 4096))[i * 256 + tid];
    __syncthreads();
#pragma unroll 8
    for (int k = 0; k < 64; ++k) {
      float xv = sX[r * 257 + c4 * 64 + k];
      float4 wv = *(const float4*)(sW + k * 64 + g * 4);
      acc[0] += xv * wv.x; acc[1] += xv * wv.y; acc[2] += xv * wv.z; acc[3] += xv * wv.w;
    }
  }
#pragma unroll
  for (int j = 0; j < 4; ++j) {
    int c = g * 4 + j;
    sH[r * 68 + c] = fmaxf(acc[j] + bc1[c], 0.f);
  }
  __syncthreads();
  if (tid < 16) {
    float l0 = bc2[0], l1 = bc2[1];
    for (int c = 0; c < 64; ++c) {
      float h = sH[tid * 68 + c];
      l0 += h * Wc2[c * 2]; l1 += h * Wc2[c * 2 + 1];
    }
    float mx = fmaxf(l0, l1);
    float lse = mx + logf(__expf(l0 - mx) + __expf(l1 - mx));
    int rowg = blk * 16 + tid;
    lp[rowg * 2]     = l0 - lse;
    lp[rowg * 2 + 1] = l1 - lse;
  }
}

// ---------------- K5: gather selected ----------------
__global__ __launch_bounds__(256) void k5_select(
    const float* __restrict__ feats, const int* __restrict__ six,
    float* __restrict__ sel) {
  int b = blockIdx.x, tid = threadIdx.x;
  int ix = six[b];
  sel[b * 256 + tid] = feats[((size_t)b * 512 + ix) * 256 + tid];
}

extern "C" void kernel_launch(void* const* d_in, const int* in_sizes, int n_in,
                              void* d_out, int out_size, void* d_ws, size_t ws_size,
                              hipStream_t stream) {
  const float* img = (const float*)d_in[0];
  const float* phr = (const float*)d_in[1];
  // d_in[2] = masks (unused by reference)
  const int*   six = (const int*)d_in[3];
  const float* Wc  = (const float*)d_in[4];
  const float* bc  = (const float*)d_in[5];
  const float* Wp  = (const float*)d_in[6];
  const float* bp  = (const float*)d_in[7];
  const float* Wih = (const float*)d_in[8];
  const float* bih = (const float*)d_in[9];
  const float* Whh = (const float*)d_in[10];
  const float* bhh = (const float*)d_in[11];
  const float* Wc1 = (const float*)d_in[12];
  const float* bc1 = (const float*)d_in[13];
  const float* Wc2 = (const float*)d_in[14];
  const float* bc2 = (const float*)d_in[15];

  float* out_lp   = (float*)d_out;        // (64,512,2)
  float* out_feat = out_lp + 65536;       // (64,512,256)
  float* out_sel  = out_feat + 8388608;   // (64,256)

  char* ws = (char*)d_ws;
  float*          emb   = (float*)ws;                              // 16 KB
  unsigned short* fuse  = (unsigned short*)(ws + 16384);           // 4 MB bf16
  unsigned*       hbuf  = (unsigned*)(ws + 4210688);               // 128 KB tagged mailbox
  unsigned short* Wpk   = (unsigned short*)(ws + 4341760);         // 640 KB packed weights

  hipLaunchKernelGGL(k1_init_emb, dim3(64), dim3(256), 0, stream,
                     phr, Wp, bp, Wih, Whh, emb, hbuf, Wpk);
  hipLaunchKernelGGL(k2_imgfuse, dim3(1024), dim3(256), 0, stream,
                     img, Wc, bc, emb, fuse);
  hipLaunchKernelGGL(k3_lstm, dim3(32), dim3(256), 0, stream,
                     Wpk, bih, bhh, fuse, hbuf, out_feat);
  hipLaunchKernelGGL(k4_classifier, dim3(2048), dim3(256), 0, stream,
                     out_feat, Wc1, bc1, Wc2, bc2, out_lp);
  hipLaunchKernelGGL(k5_select, dim3(64), dim3(256), 0, stream,
                     out_feat, six, out_sel);
}